// Round 2
// baseline (243.307 us; speedup 1.0000x reference)
//
#include <hip/hip_runtime.h>
#include <math.h>

#define D_MODEL 1024
#define RANK    64
#define PMAX    16
#define S_LEN   1024
#define HD      64
#define MROWS   4096   // B*S
#define NHEAD   16
#define BATCH   4
#define KCMAX   (PMAX * RANK)   // 1024: max composed inner dim

typedef short short8v __attribute__((ext_vector_type(8)));
typedef float floatx4 __attribute__((ext_vector_type(4)));

typedef __attribute__((address_space(1))) const unsigned int* gptr_t;
typedef __attribute__((address_space(3))) unsigned int* lptr_t;

// async global->LDS, 16 bytes per lane (global_load_lds_dwordx4)
static __device__ __forceinline__ void async16(const void* g, void* l) {
    __builtin_amdgcn_global_load_lds((gptr_t)g, (lptr_t)l, 16, 0, 0);
}

// fp32 -> bf16 bits, round-to-nearest-even (finite inputs only)
static __device__ __forceinline__ short f2bf(float f) {
    unsigned int u = __float_as_uint(f);
    u = (u + 0x7fffu + ((u >> 16) & 1u)) >> 16;
    return (short)u;
}

// ---------------------------------------------------------------------------
// Kernel 0: softmax -> top-k -> renormalize (== softmax over selected logits)
// ---------------------------------------------------------------------------
__global__ void topk_weights_kernel(const float* __restrict__ ql,
                                    const float* __restrict__ kl,
                                    const float* __restrict__ vl,
                                    const int* __restrict__ topk,
                                    int* __restrict__ idx_out,     // [3][16]
                                    float* __restrict__ w_out) {   // [3][16]
    int bank = threadIdx.x;
    if (bank >= 3) return;
    const float* lg = (bank == 0) ? ql : (bank == 1) ? kl : vl;
    int K = *topk; if (K < 1) K = 1; if (K > PMAX) K = PMAX;
    float l[PMAX];
    for (int i = 0; i < PMAX; ++i) l[i] = lg[i];
    bool used[PMAX];
    for (int i = 0; i < PMAX; ++i) used[i] = false;
    int   sel_i[PMAX];
    float sel_l[PMAX];
    for (int j = 0; j < K; ++j) {
        int best = -1; float bv = -INFINITY;
        for (int i = 0; i < PMAX; ++i)
            if (!used[i] && l[i] > bv) { bv = l[i]; best = i; }
        used[best] = true; sel_i[j] = best; sel_l[j] = bv;
    }
    float mx = sel_l[0];
    float e[PMAX];
    float sum = 0.f;
    for (int j = 0; j < K; ++j) { e[j] = __expf(sel_l[j] - mx); sum += e[j]; }
    float inv = 1.f / sum;
    for (int j = 0; j < PMAX; ++j) {
        idx_out[bank * PMAX + j] = (j < K) ? sel_i[j] : 0;
        w_out[bank * PMAX + j]   = (j < K) ? e[j] * inv : 0.f;
    }
}

// ---------------------------------------------------------------------------
// elementwise fp32 -> bf16 (vectorized)
// ---------------------------------------------------------------------------
__global__ __launch_bounds__(256) void convert_bf16_kernel(
    const float* __restrict__ src, short* __restrict__ dst, int n4) {
    int i = blockIdx.x * 256 + threadIdx.x;
    if (i < n4) {
        float4 f = ((const float4*)src)[i];
        short4 o;
        o.x = f2bf(f.x); o.y = f2bf(f.y); o.z = f2bf(f.z); o.w = f2bf(f.w);
        ((short4*)dst)[i] = o;
    }
}

// ---------------------------------------------------------------------------
// prep: build bf16 composition operands (only j < K slots are written/read):
//  z in 0..2: Uc[bank][d][j*64+r]  = U_bank[p_j][d][r]     (direct gather)
//  z in 3..5: Vt[bank][n][j*64+r]  = w_j * V_bank[p_j][r][n]  (LDS transpose)
// Both are [1024][KCMAX] bf16, row stride KCMAX.
// ---------------------------------------------------------------------------
__global__ __launch_bounds__(256) void prep_uv_kernel(
    const float* __restrict__ qU, const float* __restrict__ kU,
    const float* __restrict__ vU,
    const float* __restrict__ qV, const float* __restrict__ kV,
    const float* __restrict__ vV,
    const int* __restrict__ idx, const float* __restrict__ wsel,
    const int* __restrict__ topk,
    short* __restrict__ Uc, short* __restrict__ Vt) {
    int z    = blockIdx.z;     // 0..5
    int j    = blockIdx.y;     // 0..15
    int tile = blockIdx.x;     // 0..15
    int t    = threadIdx.x;
    int K = *topk; if (K < 1) K = 1; if (K > PMAX) K = PMAX;
    if (j >= K) return;        // unused primitive slot (uniform per block)
    __shared__ float T[64][65];
    int bank = (z < 3) ? z : z - 3;
    int p = idx[bank * PMAX + j];

    if (z < 3) {
        // U[p] is [d][r] row-major already -> straight gather, no transpose
        const float* U = (bank == 0) ? qU : (bank == 1) ? kU : vU;
        const float* src = U + (size_t)p * D_MODEL * RANK;
        short* dst = Uc + (size_t)bank * D_MODEL * KCMAX;
        int r4 = (t & 15) * 4;     // 0,4,...,60
        int dl = t >> 4;           // 0..15
#pragma unroll
        for (int i = 0; i < 4; ++i) {
            int d = tile * 64 + i * 16 + dl;
            float4 f = *(const float4*)&src[(size_t)d * RANK + r4];
            short4 o;
            o.x = f2bf(f.x); o.y = f2bf(f.y); o.z = f2bf(f.z); o.w = f2bf(f.w);
            *(short4*)&dst[(size_t)d * KCMAX + j * 64 + r4] = o;
        }
    } else {
        const float* V = (bank == 0) ? qV : (bank == 1) ? kV : vV;
        float wj = wsel[bank * PMAX + j];
        const float* src = V + (size_t)p * RANK * D_MODEL;    // [r][n]
        int n0 = tile * 64;
        int nl = t & 63, rq = t >> 6;
#pragma unroll
        for (int i = 0; i < 16; ++i) {
            int rl = i * 4 + rq;
            T[nl][rl] = src[(size_t)rl * D_MODEL + n0 + nl] * wj;
        }
        __syncthreads();
        short* dst = Vt + (size_t)bank * D_MODEL * KCMAX;
        int rr = t >> 2;
#pragma unroll
        for (int i = 0; i < 4; ++i) {
            int c = (t & 3) * 16 + i * 4;
            short4 o;
            o.x = f2bf(T[rr][c + 0]); o.y = f2bf(T[rr][c + 1]);
            o.z = f2bf(T[rr][c + 2]); o.w = f2bf(T[rr][c + 3]);
            *(short4*)&dst[(size_t)(n0 + rr) * KCMAX + j * 64 + c] = o;
        }
    }
}

// ---------------------------------------------------------------------------
// m97-style bf16 MFMA GEMM tile body: C[128x128] += A[128xkl] * B^T[128xkl]
// A: [m][k] stride lda bf16; B: [n][k] stride ldb bf16. 256 thr = 4 waves,
// wave (wm,wn) owns 64x64; per 32-k step: 8 ds_read_b128 + 16 MFMA.
// ---------------------------------------------------------------------------
static __device__ __forceinline__ void mfma_gemm_tile(
    const short* __restrict__ A, const short* __restrict__ B, int kl,
    int lda, int ldb, int m0, int n0, short* As, short* Bs, floatx4 acc[4][4]) {
    const int t    = threadIdx.x;
    const int w    = t >> 6;
    const int lane = t & 63;
    const int wm   = w & 1, wn = w >> 1;
    const int colL = lane & 15, quad = lane >> 4;
    const int srow  = lane >> 2;        // 0..15
    const int skoff = (lane & 3) * 8;   // 8-short (16B) chunk

#pragma unroll
    for (int i = 0; i < 4; ++i)
#pragma unroll
        for (int j = 0; j < 4; ++j) acc[i][j] = (floatx4){0.f, 0.f, 0.f, 0.f};

    for (int k0 = 0; k0 < kl; k0 += 32) {
        async16(A + (size_t)(m0 + w * 16 + srow) * lda + k0 + skoff,
                As + (w * 16 + srow) * 32 + skoff);
        async16(A + (size_t)(m0 + 64 + w * 16 + srow) * lda + k0 + skoff,
                As + (64 + w * 16 + srow) * 32 + skoff);
        async16(B + (size_t)(n0 + w * 16 + srow) * ldb + k0 + skoff,
                Bs + (w * 16 + srow) * 32 + skoff);
        async16(B + (size_t)(n0 + 64 + w * 16 + srow) * ldb + k0 + skoff,
                Bs + (64 + w * 16 + srow) * 32 + skoff);
        __syncthreads();
        short8v af[4], bf[4];
#pragma unroll
        for (int i = 0; i < 4; ++i)
            af[i] = *(const short8v*)&As[(wm * 64 + i * 16 + colL) * 32 + quad * 8];
#pragma unroll
        for (int j = 0; j < 4; ++j)
            bf[j] = *(const short8v*)&Bs[(wn * 64 + j * 16 + colL) * 32 + quad * 8];
#pragma unroll
        for (int i = 0; i < 4; ++i)
#pragma unroll
            for (int j = 0; j < 4; ++j)
                acc[i][j] = __builtin_amdgcn_mfma_f32_16x16x32_bf16(af[i], bf[j], acc[i][j], 0, 0, 0);
        __syncthreads();
    }
}

// ---------------------------------------------------------------------------
// Kernel 1: Wt[bank][n][d] = W_eff^T = Vt(as A) x Uc(as B), inner K*64.
//  C[m=n][n'=d] = sum_kk Vt[n][kk] * Uc[d][kk] = W_eff[d][n]  -> row-major Wt.
// ---------------------------------------------------------------------------
__global__ __launch_bounds__(256) void gemm_weff_kernel(
    const short* __restrict__ Vt, const short* __restrict__ Uc,
    const int* __restrict__ topk, short* __restrict__ Wt) {
    int K = *topk; if (K < 1) K = 1; if (K > PMAX) K = PMAX;
    int m0 = blockIdx.x * 128;   // n (output-column) dim
    int n0 = blockIdx.y * 128;   // d dim
    int bank = blockIdx.z;
    __shared__ short As[128 * 32];
    __shared__ short Bs[128 * 32];
    floatx4 acc[4][4];
    mfma_gemm_tile(Vt + (size_t)bank * D_MODEL * KCMAX,
                   Uc + (size_t)bank * D_MODEL * KCMAX,
                   K * 64, KCMAX, KCMAX, m0, n0, As, Bs, acc);

    const int t = threadIdx.x, w = t >> 6, lane = t & 63;
    const int wm = w & 1, wn = w >> 1, colL = lane & 15, quad = lane >> 4;
    short* Wb = Wt + (size_t)bank * D_MODEL * D_MODEL;
#pragma unroll
    for (int i = 0; i < 4; ++i)
#pragma unroll
        for (int j = 0; j < 4; ++j)
#pragma unroll
            for (int r = 0; r < 4; ++r)
                Wb[(size_t)(m0 + wm * 64 + i * 16 + quad * 4 + r) * D_MODEL +
                   (n0 + wn * 64 + j * 16 + colL)] = f2bf(acc[i][j][r]);
}

// ---------------------------------------------------------------------------
// Kernel 2: qkv[bank] = x @ W_eff[bank]  (B operand = Wt, already B^T layout)
//  -> bf16 [3][B*H][S][D]
// ---------------------------------------------------------------------------
__global__ __launch_bounds__(256) void gemm_qkv_kernel(
    const short* __restrict__ xb, const short* __restrict__ Wt,
    short* __restrict__ qkv) {
    int m0 = blockIdx.x * 128;
    int n0 = blockIdx.y * 128;
    int bank = blockIdx.z;
    __shared__ short As[128 * 32];
    __shared__ short Bs[128 * 32];
    floatx4 acc[4][4];
    mfma_gemm_tile(xb, Wt + (size_t)bank * D_MODEL * D_MODEL,
                   D_MODEL, D_MODEL, D_MODEL, m0, n0, As, Bs, acc);

    const int t = threadIdx.x, w = t >> 6, lane = t & 63;
    const int wm = w & 1, wn = w >> 1, colL = lane & 15, quad = lane >> 4;
    short* outp = qkv + (size_t)bank * MROWS * D_MODEL;
#pragma unroll
    for (int i = 0; i < 4; ++i)
#pragma unroll
        for (int j = 0; j < 4; ++j)
#pragma unroll
            for (int r = 0; r < 4; ++r) {
                int m = m0 + wm * 64 + i * 16 + quad * 4 + r;
                int n = n0 + wn * 64 + j * 16 + colL;
                int b = m >> 10, s = m & 1023;
                int head = n >> 6, d = n & 63;
                outp[(((size_t)(b * NHEAD + head) << 10) + s) * HD + d] = f2bf(acc[i][j][r]);
            }
}

// ---------------------------------------------------------------------------
// Kernel 4: out = attn(bf16) @ out_w(bf16)^T -> fp32 d_out
// ---------------------------------------------------------------------------
__global__ __launch_bounds__(256) void gemm_proj_kernel(
    const short* __restrict__ attnb, const short* __restrict__ wb,
    float* __restrict__ outp) {
    int m0 = blockIdx.x * 128;
    int n0 = blockIdx.y * 128;
    __shared__ short As[128 * 32];
    __shared__ short Bs[128 * 32];
    floatx4 acc[4][4];
    mfma_gemm_tile(attnb, wb, D_MODEL, D_MODEL, D_MODEL, m0, n0, As, Bs, acc);

    const int t = threadIdx.x, w = t >> 6, lane = t & 63;
    const int wm = w & 1, wn = w >> 1, colL = lane & 15, quad = lane >> 4;
#pragma unroll
    for (int i = 0; i < 4; ++i)
#pragma unroll
        for (int j = 0; j < 4; ++j)
#pragma unroll
            for (int r = 0; r < 4; ++r)
                outp[(size_t)(m0 + wm * 64 + i * 16 + quad * 4 + r) * D_MODEL +
                     (n0 + wn * 64 + j * 16 + colL)] = acc[i][j][r];
}

// ---------------------------------------------------------------------------
// Kernel 3: causal flash attention, bf16 MFMA (16x16x32). Output bf16.
// One q-tile per block; qt = 15 - blockIdx.x so heaviest blocks launch first.
// ---------------------------------------------------------------------------
__global__ __launch_bounds__(256) void attn_mfma_kernel(
    const short* __restrict__ qkv,    // bf16 [3][BH=64][S=1024][D=64]
    short* __restrict__ attn_out) {   // bf16 [B=4][S=1024][H*D=1024]
    const int t    = threadIdx.x;
    const int w    = t >> 6;
    const int lane = t & 63;
    const int col  = lane & 15;
    const int quad = lane >> 4;
    const int qt   = 15 - (int)blockIdx.x;   // 0..15, heavy first
    const int bh   = blockIdx.y;             // 0..63
    const size_t HS   = (size_t)S_LEN * HD;
    const size_t BSTR = (size_t)MROWS * D_MODEL;
    const short* Qg = qkv + (size_t)bh * HS;
    const short* Kg = qkv + BSTR + (size_t)bh * HS;
    const short* Vg = qkv + 2 * BSTR + (size_t)bh * HS;

    __shared__ short Ks[64][72];      // [key][d]
    __shared__ short Vt[64][72];      // [d][key] (transposed)
    __shared__ short Ps[4][16][72];   // per-wave P [q][key]

    const float SC = 0.125f * 1.44269504f;   // 1/sqrt(64) * log2(e)

    const int qrow = qt * 64 + w * 16 + col;
    short8v aq0 = *(const short8v*)(Qg + (size_t)qrow * HD + quad * 8);
    short8v aq1 = *(const short8v*)(Qg + (size_t)qrow * HD + 32 + quad * 8);
    floatx4 O0 = {0.f, 0.f, 0.f, 0.f}, O1 = O0, O2 = O0, O3 = O0;
    float mrow[4] = {-INFINITY, -INFINITY, -INFINITY, -INFINITY};
    float lrow[4] = {0.f, 0.f, 0.f, 0.f};

    for (int jt = 0; jt <= qt; ++jt) {
        __syncthreads();
        // ---- stage K tile (row-major) ----
        {
            int c = t;
            int key = c >> 3, db = (c & 7) * 8;
            *(short8v*)&Ks[key][db] =
                *(const short8v*)(Kg + (size_t)(jt * 64 + key) * HD + db);
            c = t + 256;
            key = c >> 3; db = (c & 7) * 8;
            *(short8v*)&Ks[key][db] =
                *(const short8v*)(Kg + (size_t)(jt * 64 + key) * HD + db);
        }
        // ---- stage V tile transposed (packed pair writes) ----
        {
            int k0 = (t & 31) * 2;
            int db = (t >> 5) * 8;
            short8v v0 = *(const short8v*)(Vg + (size_t)(jt * 64 + k0) * HD + db);
            short8v v1 = *(const short8v*)(Vg + (size_t)(jt * 64 + k0 + 1) * HD + db);
#pragma unroll
            for (int i = 0; i < 8; ++i) {
                unsigned int pk = (unsigned int)(unsigned short)v0[i] |
                                  ((unsigned int)(unsigned short)v1[i] << 16);
                *(unsigned int*)&Vt[db + i][k0] = pk;
            }
        }
        __syncthreads();

        const bool diag = (jt == qt);
        const int  nmax = diag ? w : 3;
        float sc[4][4];
#pragma unroll
        for (int n = 0; n < 4; ++n) {
            if (n <= nmax) {
                floatx4 c4 = {0.f, 0.f, 0.f, 0.f};
                short8v b0 = *(const short8v*)&Ks[n * 16 + col][quad * 8];
                short8v b1 = *(const short8v*)&Ks[n * 16 + col][32 + quad * 8];
                c4 = __builtin_amdgcn_mfma_f32_16x16x32_bf16(aq0, b0, c4, 0, 0, 0);
                c4 = __builtin_amdgcn_mfma_f32_16x16x32_bf16(aq1, b1, c4, 0, 0, 0);
#pragma unroll
                for (int r = 0; r < 4; ++r) {
                    float v = c4[r] * SC;
                    if (diag && n == w && col > quad * 4 + r) v = -INFINITY;
                    sc[n][r] = v;
                }
            } else {
#pragma unroll
                for (int r = 0; r < 4; ++r) sc[n][r] = -INFINITY;
            }
        }
        // ---- online softmax (exp2 domain), per q-row ----
        float pv[4][4];
#pragma unroll
        for (int r = 0; r < 4; ++r) {
            float tm = fmaxf(fmaxf(sc[0][r], sc[1][r]), fmaxf(sc[2][r], sc[3][r]));
            tm = fmaxf(tm, __shfl_xor(tm, 1));
            tm = fmaxf(tm, __shfl_xor(tm, 2));
            tm = fmaxf(tm, __shfl_xor(tm, 4));
            tm = fmaxf(tm, __shfl_xor(tm, 8));
            float mnew  = fmaxf(mrow[r], tm);
            float alpha = exp2f(mrow[r] - mnew);
            float ps = 0.f;
#pragma unroll
            for (int n = 0; n < 4; ++n) {
                float p = exp2f(sc[n][r] - mnew);
                pv[n][r] = p;
                ps += p;
            }
            ps += __shfl_xor(ps, 1);
            ps += __shfl_xor(ps, 2);
            ps += __shfl_xor(ps, 4);
            ps += __shfl_xor(ps, 8);
            lrow[r] = lrow[r] * alpha + ps;
            mrow[r] = mnew;
            O0[r] *= alpha; O1[r] *= alpha; O2[r] *= alpha; O3[r] *= alpha;
        }
        // ---- P -> LDS (C-layout -> A-layout transform) ----
#pragma unroll
        for (int n = 0; n < 4; ++n)
#pragma unroll
            for (int r = 0; r < 4; ++r)
                Ps[w][quad * 4 + r][n * 16 + col] = f2bf(pv[n][r]);
        // ---- PV MFMAs ----
        const int ksmax = diag ? (w >> 1) : 1;
#pragma unroll
        for (int ks = 0; ks < 2; ++ks) {
            if (ks > ksmax) break;
            short8v ap  = *(const short8v*)&Ps[w][col][ks * 32 + quad * 8];
            short8v bv0 = *(const short8v*)&Vt[0  + col][ks * 32 + quad * 8];
            short8v bv1 = *(const short8v*)&Vt[16 + col][ks * 32 + quad * 8];
            short8v bv2 = *(const short8v*)&Vt[32 + col][ks * 32 + quad * 8];
            short8v bv3 = *(const short8v*)&Vt[48 + col][ks * 32 + quad * 8];
            O0 = __builtin_amdgcn_mfma_f32_16x16x32_bf16(ap, bv0, O0, 0, 0, 0);
            O1 = __builtin_amdgcn_mfma_f32_16x16x32_bf16(ap, bv1, O1, 0, 0, 0);
            O2 = __builtin_amdgcn_mfma_f32_16x16x32_bf16(ap, bv2, O2, 0, 0, 0);
            O3 = __builtin_amdgcn_mfma_f32_16x16x32_bf16(ap, bv3, O3, 0, 0, 0);
        }
    }
    // ---- epilogue: normalize + store bf16 [B][S][H*D] ----
    const int b  = bh >> 4;
    const int hh = bh & 15;
    short* orow = attn_out +
        ((size_t)(b * S_LEN) + qt * 64 + w * 16) * D_MODEL + hh * 64;
#pragma unroll
    for (int r = 0; r < 4; ++r) {
        float inv = 1.f / lrow[r];
        short* prw = orow + (size_t)(quad * 4 + r) * D_MODEL;
        prw[0  + col] = f2bf(O0[r] * inv);
        prw[16 + col] = f2bf(O1[r] * inv);
        prw[32 + col] = f2bf(O2[r] * inv);
        prw[48 + col] = f2bf(O3[r] * inv);
    }
}

// ---------------------------------------------------------------------------
extern "C" void kernel_launch(void* const* d_in, const int* in_sizes, int n_in,
                              void* d_out, int out_size, void* d_ws, size_t ws_size,
                              hipStream_t stream) {
    const float* x    = (const float*)d_in[0];
    const float* qU   = (const float*)d_in[1];
    const float* qV   = (const float*)d_in[2];
    const float* kU   = (const float*)d_in[3];
    const float* kV   = (const float*)d_in[4];
    const float* vU   = (const float*)d_in[5];
    const float* vV   = (const float*)d_in[6];
    const float* qlg  = (const float*)d_in[7];
    const float* klg  = (const float*)d_in[8];
    const float* vlg  = (const float*)d_in[9];
    const float* outw = (const float*)d_in[10];
    const int*   topk = (const int*)d_in[11];
    float* outp = (float*)d_out;

    char* ws = (char*)d_ws;
    int*   idxp = (int*)ws;                              // [3][16]
    float* wp   = (float*)(ws + 256);                    // [3][16]
    short* xb   = (short*)(ws + 512);                    // 8 MB
    short* Uc   = xb + (size_t)MROWS * D_MODEL;          // 6 MB [3][1024][KCMAX]
    short* Vt   = Uc + (size_t)3 * D_MODEL * KCMAX;      // 6 MB [3][1024][KCMAX]
    short* wb   = Vt + (size_t)3 * D_MODEL * KCMAX;      // 2 MB
    short* Wt   = wb + (size_t)D_MODEL * D_MODEL;        // 6 MB [3][1024][1024]
    short* qkvb = Wt + (size_t)3 * D_MODEL * D_MODEL;    // 24 MB
    short* attnb = qkvb + (size_t)3 * MROWS * D_MODEL;   // 8 MB

    topk_weights_kernel<<<1, 64, 0, stream>>>(qlg, klg, vlg, topk, idxp, wp);
    convert_bf16_kernel<<<(MROWS * D_MODEL / 4 + 255) / 256, 256, 0, stream>>>(
        x, xb, MROWS * D_MODEL / 4);
    convert_bf16_kernel<<<(D_MODEL * D_MODEL / 4 + 255) / 256, 256, 0, stream>>>(
        outw, wb, D_MODEL * D_MODEL / 4);
    prep_uv_kernel<<<dim3(16, 16, 6), 256, 0, stream>>>(
        qU, kU, vU, qV, kV, vV, idxp, wp, topk, Uc, Vt);
    gemm_weff_kernel<<<dim3(8, 8, 3), 256, 0, stream>>>(Vt, Uc, topk, Wt);
    gemm_qkv_kernel<<<dim3(32, 8, 3), 256, 0, stream>>>(xb, Wt, qkvb);
    attn_mfma_kernel<<<dim3(16, 64), 256, 0, stream>>>(qkvb, attnb);
    gemm_proj_kernel<<<dim3(32, 8), 256, 0, stream>>>(attnb, wb, outp);
}

// Round 3
// 222.810 us; speedup vs baseline: 1.0920x; 1.0920x over previous
//
#include <hip/hip_runtime.h>
#include <math.h>

#define D_MODEL 1024
#define RANK    64
#define PMAX    16
#define S_LEN   1024
#define HD      64
#define MROWS   4096   // B*S
#define NHEAD   16
#define BATCH   4
#define KCMAX   (PMAX * RANK)   // 1024: max composed inner dim

typedef short short8v __attribute__((ext_vector_type(8)));
typedef float floatx4 __attribute__((ext_vector_type(4)));

typedef __attribute__((address_space(1))) const unsigned int* gptr_t;
typedef __attribute__((address_space(3))) unsigned int* lptr_t;

// async global->LDS, 16 bytes per lane (global_load_lds_dwordx4)
static __device__ __forceinline__ void async16(const void* g, void* l) {
    __builtin_amdgcn_global_load_lds((gptr_t)g, (lptr_t)l, 16, 0, 0);
}

// fp32 -> bf16 bits, round-to-nearest-even (finite inputs only)
static __device__ __forceinline__ short f2bf(float f) {
    unsigned int u = __float_as_uint(f);
    u = (u + 0x7fffu + ((u >> 16) & 1u)) >> 16;
    return (short)u;
}

// ---------------------------------------------------------------------------
// Kernel 0: softmax -> top-k -> renormalize (== softmax over selected logits)
// ---------------------------------------------------------------------------
__global__ void topk_weights_kernel(const float* __restrict__ ql,
                                    const float* __restrict__ kl,
                                    const float* __restrict__ vl,
                                    const int* __restrict__ topk,
                                    int* __restrict__ idx_out,     // [3][16]
                                    float* __restrict__ w_out) {   // [3][16]
    int bank = threadIdx.x;
    if (bank >= 3) return;
    const float* lg = (bank == 0) ? ql : (bank == 1) ? kl : vl;
    int K = *topk; if (K < 1) K = 1; if (K > PMAX) K = PMAX;
    float l[PMAX];
    for (int i = 0; i < PMAX; ++i) l[i] = lg[i];
    bool used[PMAX];
    for (int i = 0; i < PMAX; ++i) used[i] = false;
    int   sel_i[PMAX];
    float sel_l[PMAX];
    for (int j = 0; j < K; ++j) {
        int best = -1; float bv = -INFINITY;
        for (int i = 0; i < PMAX; ++i)
            if (!used[i] && l[i] > bv) { bv = l[i]; best = i; }
        used[best] = true; sel_i[j] = best; sel_l[j] = bv;
    }
    float mx = sel_l[0];
    float e[PMAX];
    float sum = 0.f;
    for (int j = 0; j < K; ++j) { e[j] = __expf(sel_l[j] - mx); sum += e[j]; }
    float inv = 1.f / sum;
    for (int j = 0; j < PMAX; ++j) {
        idx_out[bank * PMAX + j] = (j < K) ? sel_i[j] : 0;
        w_out[bank * PMAX + j]   = (j < K) ? e[j] * inv : 0.f;
    }
}

// ---------------------------------------------------------------------------
// elementwise fp32 -> bf16 (vectorized)
// ---------------------------------------------------------------------------
__global__ __launch_bounds__(256) void convert_bf16_kernel(
    const float* __restrict__ src, short* __restrict__ dst, int n4) {
    int i = blockIdx.x * 256 + threadIdx.x;
    if (i < n4) {
        float4 f = ((const float4*)src)[i];
        short4 o;
        o.x = f2bf(f.x); o.y = f2bf(f.y); o.z = f2bf(f.z); o.w = f2bf(f.w);
        ((short4*)dst)[i] = o;
    }
}

// ---------------------------------------------------------------------------
// prep: build bf16 composition operands (only j < K slots are written/read):
//  z in 0..2: Uc[bank][d][j*64+r]  = U_bank[p_j][d][r]     (direct gather)
//  z in 3..5: Vt[bank][n][j*64+r]  = w_j * V_bank[p_j][r][n]  (LDS transpose)
// ---------------------------------------------------------------------------
__global__ __launch_bounds__(256) void prep_uv_kernel(
    const float* __restrict__ qU, const float* __restrict__ kU,
    const float* __restrict__ vU,
    const float* __restrict__ qV, const float* __restrict__ kV,
    const float* __restrict__ vV,
    const int* __restrict__ idx, const float* __restrict__ wsel,
    const int* __restrict__ topk,
    short* __restrict__ Uc, short* __restrict__ Vt) {
    int z    = blockIdx.z;     // 0..5
    int j    = blockIdx.y;     // 0..15
    int tile = blockIdx.x;     // 0..15
    int t    = threadIdx.x;
    int K = *topk; if (K < 1) K = 1; if (K > PMAX) K = PMAX;
    if (j >= K) return;        // unused primitive slot (uniform per block)
    __shared__ float T[64][65];
    int bank = (z < 3) ? z : z - 3;
    int p = idx[bank * PMAX + j];

    if (z < 3) {
        const float* U = (bank == 0) ? qU : (bank == 1) ? kU : vU;
        const float* src = U + (size_t)p * D_MODEL * RANK;
        short* dst = Uc + (size_t)bank * D_MODEL * KCMAX;
        int r4 = (t & 15) * 4;
        int dl = t >> 4;
#pragma unroll
        for (int i = 0; i < 4; ++i) {
            int d = tile * 64 + i * 16 + dl;
            float4 f = *(const float4*)&src[(size_t)d * RANK + r4];
            short4 o;
            o.x = f2bf(f.x); o.y = f2bf(f.y); o.z = f2bf(f.z); o.w = f2bf(f.w);
            *(short4*)&dst[(size_t)d * KCMAX + j * 64 + r4] = o;
        }
    } else {
        const float* V = (bank == 0) ? qV : (bank == 1) ? kV : vV;
        float wj = wsel[bank * PMAX + j];
        const float* src = V + (size_t)p * RANK * D_MODEL;    // [r][n]
        int n0 = tile * 64;
        int nl = t & 63, rq = t >> 6;
#pragma unroll
        for (int i = 0; i < 16; ++i) {
            int rl = i * 4 + rq;
            T[nl][rl] = src[(size_t)rl * D_MODEL + n0 + nl] * wj;
        }
        __syncthreads();
        short* dst = Vt + (size_t)bank * D_MODEL * KCMAX;
        int rr = t >> 2;
#pragma unroll
        for (int i = 0; i < 4; ++i) {
            int c = (t & 3) * 16 + i * 4;
            short4 o;
            o.x = f2bf(T[rr][c + 0]); o.y = f2bf(T[rr][c + 1]);
            o.z = f2bf(T[rr][c + 2]); o.w = f2bf(T[rr][c + 3]);
            *(short4*)&dst[(size_t)(n0 + rr) * KCMAX + j * 64 + c] = o;
        }
    }
}

// ---------------------------------------------------------------------------
// m97-style bf16 MFMA GEMM tile body: C[128x128] += A[128xkl] * B^T[128xkl]
// ---------------------------------------------------------------------------
static __device__ __forceinline__ void mfma_gemm_tile(
    const short* __restrict__ A, const short* __restrict__ B, int kl,
    int lda, int ldb, int m0, int n0, short* As, short* Bs, floatx4 acc[4][4]) {
    const int t    = threadIdx.x;
    const int w    = t >> 6;
    const int lane = t & 63;
    const int wm   = w & 1, wn = w >> 1;
    const int colL = lane & 15, quad = lane >> 4;
    const int srow  = lane >> 2;        // 0..15
    const int skoff = (lane & 3) * 8;   // 8-short (16B) chunk

#pragma unroll
    for (int i = 0; i < 4; ++i)
#pragma unroll
        for (int j = 0; j < 4; ++j) acc[i][j] = (floatx4){0.f, 0.f, 0.f, 0.f};

    for (int k0 = 0; k0 < kl; k0 += 32) {
        async16(A + (size_t)(m0 + w * 16 + srow) * lda + k0 + skoff,
                As + (w * 16 + srow) * 32 + skoff);
        async16(A + (size_t)(m0 + 64 + w * 16 + srow) * lda + k0 + skoff,
                As + (64 + w * 16 + srow) * 32 + skoff);
        async16(B + (size_t)(n0 + w * 16 + srow) * ldb + k0 + skoff,
                Bs + (w * 16 + srow) * 32 + skoff);
        async16(B + (size_t)(n0 + 64 + w * 16 + srow) * ldb + k0 + skoff,
                Bs + (64 + w * 16 + srow) * 32 + skoff);
        __syncthreads();
        short8v af[4], bf[4];
#pragma unroll
        for (int i = 0; i < 4; ++i)
            af[i] = *(const short8v*)&As[(wm * 64 + i * 16 + colL) * 32 + quad * 8];
#pragma unroll
        for (int j = 0; j < 4; ++j)
            bf[j] = *(const short8v*)&Bs[(wn * 64 + j * 16 + colL) * 32 + quad * 8];
#pragma unroll
        for (int i = 0; i < 4; ++i)
#pragma unroll
            for (int j = 0; j < 4; ++j)
                acc[i][j] = __builtin_amdgcn_mfma_f32_16x16x32_bf16(af[i], bf[j], acc[i][j], 0, 0, 0);
        __syncthreads();
    }
}

// ---------------------------------------------------------------------------
// Kernel 1: Wt[bank][n][d] = W_eff^T = Vt(as A) x Uc(as B), inner K*64.
// ---------------------------------------------------------------------------
__global__ __launch_bounds__(256) void gemm_weff_kernel(
    const short* __restrict__ Vt, const short* __restrict__ Uc,
    const int* __restrict__ topk, short* __restrict__ Wt) {
    int K = *topk; if (K < 1) K = 1; if (K > PMAX) K = PMAX;
    // XCD-aware swizzle: 192 blocks, chunk 24 per XCD
    int id = blockIdx.x + 8 * (blockIdx.y + 8 * blockIdx.z);
    int sw = (id & 7) * 24 + (id >> 3);
    int m0 = (sw & 7) * 128; int rest = sw >> 3;
    int n0 = (rest & 7) * 128; int bank = rest >> 3;
    __shared__ short As[128 * 32];
    __shared__ short Bs[128 * 32];
    floatx4 acc[4][4];
    mfma_gemm_tile(Vt + (size_t)bank * D_MODEL * KCMAX,
                   Uc + (size_t)bank * D_MODEL * KCMAX,
                   K * 64, KCMAX, KCMAX, m0, n0, As, Bs, acc);

    const int t = threadIdx.x, w = t >> 6, lane = t & 63;
    const int wm = w & 1, wn = w >> 1, colL = lane & 15, quad = lane >> 4;
    short* Wb = Wt + (size_t)bank * D_MODEL * D_MODEL;
#pragma unroll
    for (int i = 0; i < 4; ++i)
#pragma unroll
        for (int j = 0; j < 4; ++j)
#pragma unroll
            for (int r = 0; r < 4; ++r)
                Wb[(size_t)(m0 + wm * 64 + i * 16 + quad * 4 + r) * D_MODEL +
                   (n0 + wn * 64 + j * 16 + colL)] = f2bf(acc[i][j][r]);
}

// ---------------------------------------------------------------------------
// Kernel 2: qkv[bank] = x @ W_eff[bank] -> bf16 [3][B*H][S][D]
// ---------------------------------------------------------------------------
__global__ __launch_bounds__(256) void gemm_qkv_kernel(
    const short* __restrict__ xb, const short* __restrict__ Wt,
    short* __restrict__ qkv) {
    // XCD-aware swizzle: 768 blocks, chunk 96 per XCD
    int id = blockIdx.x + 32 * (blockIdx.y + 8 * blockIdx.z);
    int sw = (id & 7) * 96 + (id >> 3);
    int m0 = (sw & 31) * 128; int rest = sw >> 5;
    int n0 = (rest & 7) * 128; int bank = rest >> 3;
    __shared__ short As[128 * 32];
    __shared__ short Bs[128 * 32];
    floatx4 acc[4][4];
    mfma_gemm_tile(xb, Wt + (size_t)bank * D_MODEL * D_MODEL,
                   D_MODEL, D_MODEL, D_MODEL, m0, n0, As, Bs, acc);

    const int t = threadIdx.x, w = t >> 6, lane = t & 63;
    const int wm = w & 1, wn = w >> 1, colL = lane & 15, quad = lane >> 4;
    short* outp = qkv + (size_t)bank * MROWS * D_MODEL;
#pragma unroll
    for (int i = 0; i < 4; ++i)
#pragma unroll
        for (int j = 0; j < 4; ++j)
#pragma unroll
            for (int r = 0; r < 4; ++r) {
                int m = m0 + wm * 64 + i * 16 + quad * 4 + r;
                int n = n0 + wn * 64 + j * 16 + colL;
                int b = m >> 10, s = m & 1023;
                int head = n >> 6, d = n & 63;
                outp[(((size_t)(b * NHEAD + head) << 10) + s) * HD + d] = f2bf(acc[i][j][r]);
            }
}

// ---------------------------------------------------------------------------
// Kernel 4: out = attn(bf16) @ out_w(bf16)^T -> fp32 d_out
// ---------------------------------------------------------------------------
__global__ __launch_bounds__(256) void gemm_proj_kernel(
    const short* __restrict__ attnb, const short* __restrict__ wb,
    float* __restrict__ outp) {
    // XCD-aware swizzle: 256 blocks, chunk 32 per XCD
    int id = blockIdx.x + 32 * blockIdx.y;
    int sw = (id & 7) * 32 + (id >> 3);
    int m0 = (sw & 31) * 128;
    int n0 = (sw >> 5) * 128;
    __shared__ short As[128 * 32];
    __shared__ short Bs[128 * 32];
    floatx4 acc[4][4];
    mfma_gemm_tile(attnb, wb, D_MODEL, D_MODEL, D_MODEL, m0, n0, As, Bs, acc);

    const int t = threadIdx.x, w = t >> 6, lane = t & 63;
    const int wm = w & 1, wn = w >> 1, colL = lane & 15, quad = lane >> 4;
#pragma unroll
    for (int i = 0; i < 4; ++i)
#pragma unroll
        for (int j = 0; j < 4; ++j)
#pragma unroll
            for (int r = 0; r < 4; ++r)
                outp[(size_t)(m0 + wm * 64 + i * 16 + quad * 4 + r) * D_MODEL +
                     (n0 + wn * 64 + j * 16 + colL)] = acc[i][j][r];
}

// ---------------------------------------------------------------------------
// Kernel 3: causal flash attention, bf16 MFMA (16x16x32). Output bf16.
// Paired 2-phase (qt = pr, 15-pr -> 9 kv-tiles per block, balanced).
// KVBLK=128 keys per iteration; defer-max online softmax (THR=8, exp2 dom).
// ---------------------------------------------------------------------------
__global__ __launch_bounds__(256) void attn_mfma_kernel(
    const short* __restrict__ qkv,    // bf16 [3][BH=64][S=1024][D=64]
    short* __restrict__ attn_out) {   // bf16 [B=4][S=1024][H*D=1024]
    const int t    = threadIdx.x;
    const int w    = t >> 6;
    const int lane = t & 63;
    const int col  = lane & 15;
    const int quad = lane >> 4;
    // XCD swizzle: 512 blocks, chunk 64 -> 8 heads per XCD (KV stays in L2)
    int id = blockIdx.x + 8 * blockIdx.y;
    int sw = (id & 7) * 64 + (id >> 3);
    const int pr = sw & 7;    // 0..7
    const int bh = sw >> 3;   // 0..63
    const size_t HS   = (size_t)S_LEN * HD;
    const size_t BSTR = (size_t)MROWS * D_MODEL;
    const short* Qg = qkv + (size_t)bh * HS;
    const short* Kg = qkv + BSTR + (size_t)bh * HS;
    const short* Vg = qkv + 2 * BSTR + (size_t)bh * HS;

    __shared__ short Ks[128][72];     // [key][d]
    __shared__ short Vt[64][136];     // [d][key] (transposed)
    __shared__ short Ps[4][16][136];  // per-wave P [q][key]

    const float SC = 0.125f * 1.44269504f;   // 1/sqrt(64) * log2(e)

    for (int ph = 0; ph < 2; ++ph) {
        const int qt = ph ? (15 - pr) : pr;
        const int qb = qt * 4 + w;            // wave's global q 16-block
        const int qrow = qt * 64 + w * 16 + col;
        short8v aq0 = *(const short8v*)(Qg + (size_t)qrow * HD + quad * 8);
        short8v aq1 = *(const short8v*)(Qg + (size_t)qrow * HD + 32 + quad * 8);
        floatx4 O0 = {0.f, 0.f, 0.f, 0.f}, O1 = O0, O2 = O0, O3 = O0;
        float mrow[4] = {-INFINITY, -INFINITY, -INFINITY, -INFINITY};
        float lrow[4] = {0.f, 0.f, 0.f, 0.f};
        const int nkv = (qt + 2) >> 1;        // 128-key tiles

        for (int jt = 0; jt < nkv; ++jt) {
            __syncthreads();
            // ---- stage K tile 128x64 (row-major) ----
#pragma unroll
            for (int it = 0; it < 4; ++it) {
                int idx = t + it * 256;
                int key = idx >> 3, db = (idx & 7) * 8;
                *(short8v*)&Ks[key][db] =
                    *(const short8v*)(Kg + (size_t)(jt * 128 + key) * HD + db);
            }
            // ---- stage V tile transposed (packed pair writes) ----
#pragma unroll
            for (int it = 0; it < 2; ++it) {
                int idx = t + it * 256;
                int k0 = (idx & 63) * 2;
                int db = (idx >> 6) * 8;
                short8v v0 = *(const short8v*)(Vg + (size_t)(jt * 128 + k0) * HD + db);
                short8v v1 = *(const short8v*)(Vg + (size_t)(jt * 128 + k0 + 1) * HD + db);
#pragma unroll
                for (int i = 0; i < 8; ++i) {
                    unsigned int pk = (unsigned int)(unsigned short)v0[i] |
                                      ((unsigned int)(unsigned short)v1[i] << 16);
                    *(unsigned int*)&Vt[db + i][k0] = pk;
                }
            }
            __syncthreads();

            // ---- QK^T scores: 8 key sub-blocks of 16 ----
            float sc[8][4];
            const int base = jt * 8;
#pragma unroll
            for (int n = 0; n < 8; ++n) {
                int rel = qb - (base + n);
                if (rel >= 0) {
                    floatx4 c4 = {0.f, 0.f, 0.f, 0.f};
                    short8v b0 = *(const short8v*)&Ks[n * 16 + col][quad * 8];
                    short8v b1 = *(const short8v*)&Ks[n * 16 + col][32 + quad * 8];
                    c4 = __builtin_amdgcn_mfma_f32_16x16x32_bf16(aq0, b0, c4, 0, 0, 0);
                    c4 = __builtin_amdgcn_mfma_f32_16x16x32_bf16(aq1, b1, c4, 0, 0, 0);
#pragma unroll
                    for (int r = 0; r < 4; ++r) {
                        float v = c4[r] * SC;
                        if (rel == 0 && col > quad * 4 + r) v = -INFINITY;
                        sc[n][r] = v;
                    }
                } else {
#pragma unroll
                    for (int r = 0; r < 4; ++r) sc[n][r] = -INFINITY;
                }
            }
            // ---- online softmax (exp2 domain) with defer-max ----
#pragma unroll
            for (int r = 0; r < 4; ++r) {
                float tm = sc[0][r];
#pragma unroll
                for (int n = 1; n < 8; ++n) tm = fmaxf(tm, sc[n][r]);
                tm = fmaxf(tm, __shfl_xor(tm, 1));
                tm = fmaxf(tm, __shfl_xor(tm, 2));
                tm = fmaxf(tm, __shfl_xor(tm, 4));
                tm = fmaxf(tm, __shfl_xor(tm, 8));
                if (__any(tm > mrow[r] + 8.0f)) {
                    float mnew  = fmaxf(mrow[r], tm);
                    float alpha = exp2f(mrow[r] - mnew);
                    lrow[r] *= alpha;
                    O0[r] *= alpha; O1[r] *= alpha; O2[r] *= alpha; O3[r] *= alpha;
                    mrow[r] = mnew;
                }
                float ps = 0.f;
#pragma unroll
                for (int n = 0; n < 8; ++n) {
                    float p = exp2f(sc[n][r] - mrow[r]);
                    ps += p;
                    Ps[w][quad * 4 + r][n * 16 + col] = f2bf(p);
                }
                ps += __shfl_xor(ps, 1);
                ps += __shfl_xor(ps, 2);
                ps += __shfl_xor(ps, 4);
                ps += __shfl_xor(ps, 8);
                lrow[r] += ps;
            }
            // ---- PV MFMAs: key chunks of 32 ----
            int lim = qb * 16 + 15 - (jt << 7);
            int ksm = lim >> 5; if (ksm > 3) ksm = 3;
#pragma unroll
            for (int ks = 0; ks < 4; ++ks) {
                if (ks > ksm) break;
                short8v ap  = *(const short8v*)&Ps[w][col][ks * 32 + quad * 8];
                short8v bv0 = *(const short8v*)&Vt[0  + col][ks * 32 + quad * 8];
                short8v bv1 = *(const short8v*)&Vt[16 + col][ks * 32 + quad * 8];
                short8v bv2 = *(const short8v*)&Vt[32 + col][ks * 32 + quad * 8];
                short8v bv3 = *(const short8v*)&Vt[48 + col][ks * 32 + quad * 8];
                O0 = __builtin_amdgcn_mfma_f32_16x16x32_bf16(ap, bv0, O0, 0, 0, 0);
                O1 = __builtin_amdgcn_mfma_f32_16x16x32_bf16(ap, bv1, O1, 0, 0, 0);
                O2 = __builtin_amdgcn_mfma_f32_16x16x32_bf16(ap, bv2, O2, 0, 0, 0);
                O3 = __builtin_amdgcn_mfma_f32_16x16x32_bf16(ap, bv3, O3, 0, 0, 0);
            }
        }
        // ---- epilogue: normalize + store bf16 [B][S][H*D] ----
        const int b  = bh >> 4;
        const int hh = bh & 15;
        short* orow = attn_out +
            ((size_t)(b * S_LEN) + qt * 64 + w * 16) * D_MODEL + hh * 64;
#pragma unroll
        for (int r = 0; r < 4; ++r) {
            float inv = 1.f / lrow[r];
            short* prw = orow + (size_t)(quad * 4 + r) * D_MODEL;
            prw[0  + col] = f2bf(O0[r] * inv);
            prw[16 + col] = f2bf(O1[r] * inv);
            prw[32 + col] = f2bf(O2[r] * inv);
            prw[48 + col] = f2bf(O3[r] * inv);
        }
    }
}

// ---------------------------------------------------------------------------
extern "C" void kernel_launch(void* const* d_in, const int* in_sizes, int n_in,
                              void* d_out, int out_size, void* d_ws, size_t ws_size,
                              hipStream_t stream) {
    const float* x    = (const float*)d_in[0];
    const float* qU   = (const float*)d_in[1];
    const float* qV   = (const float*)d_in[2];
    const float* kU   = (const float*)d_in[3];
    const float* kV   = (const float*)d_in[4];
    const float* vU   = (const float*)d_in[5];
    const float* vV   = (const float*)d_in[6];
    const float* qlg  = (const float*)d_in[7];
    const float* klg  = (const float*)d_in[8];
    const float* vlg  = (const float*)d_in[9];
    const float* outw = (const float*)d_in[10];
    const int*   topk = (const int*)d_in[11];
    float* outp = (float*)d_out;

    char* ws = (char*)d_ws;
    int*   idxp = (int*)ws;                              // [3][16]
    float* wp   = (float*)(ws + 256);                    // [3][16]
    short* xb   = (short*)(ws + 512);                    // 8 MB
    short* Uc   = xb + (size_t)MROWS * D_MODEL;          // 6 MB [3][1024][KCMAX]
    short* Vt   = Uc + (size_t)3 * D_MODEL * KCMAX;      // 6 MB [3][1024][KCMAX]
    short* wb   = Vt + (size_t)3 * D_MODEL * KCMAX;      // 2 MB
    short* Wt   = wb + (size_t)D_MODEL * D_MODEL;        // 6 MB [3][1024][1024]
    short* qkvb = Wt + (size_t)3 * D_MODEL * D_MODEL;    // 24 MB
    short* attnb = qkvb + (size_t)3 * MROWS * D_MODEL;   // 8 MB

    topk_weights_kernel<<<1, 64, 0, stream>>>(qlg, klg, vlg, topk, idxp, wp);
    convert_bf16_kernel<<<(MROWS * D_MODEL / 4 + 255) / 256, 256, 0, stream>>>(
        x, xb, MROWS * D_MODEL / 4);
    convert_bf16_kernel<<<(D_MODEL * D_MODEL / 4 + 255) / 256, 256, 0, stream>>>(
        outw, wb, D_MODEL * D_MODEL / 4);
    prep_uv_kernel<<<dim3(16, 16, 6), 256, 0, stream>>>(
        qU, kU, vU, qV, kV, vV, idxp, wp, topk, Uc, Vt);
    gemm_weff_kernel<<<dim3(8, 8, 3), 256, 0, stream>>>(Vt, Uc, topk, Wt);
    gemm_qkv_kernel<<<dim3(32, 8, 3), 256, 0, stream>>>(xb, Wt, qkvb);
    attn_mfma_kernel<<<dim3(8, 64), 256, 0, stream>>>(qkvb, attnb);
    gemm_proj_kernel<<<dim3(32, 8), 256, 0, stream>>>(attnb, wb, outp);
}

// Round 4
// 211.918 us; speedup vs baseline: 1.1481x; 1.0514x over previous
//
#include <hip/hip_runtime.h>
#include <math.h>

#define D_MODEL 1024
#define RANK    64
#define PMAX    16
#define S_LEN   1024
#define HD      64
#define MROWS   4096   // B*S
#define NHEAD   16
#define BATCH   4
#define KCMAX   (PMAX * RANK)   // 1024: max composed inner dim

typedef short short8v __attribute__((ext_vector_type(8)));
typedef short short4v __attribute__((ext_vector_type(4)));
typedef float floatx4 __attribute__((ext_vector_type(4)));

typedef __attribute__((address_space(1))) const unsigned int* gptr_t;
typedef __attribute__((address_space(3))) unsigned int* lptr_t;
typedef __attribute__((address_space(3))) short* lds3s;

// async global->LDS, 16 bytes per lane (global_load_lds_dwordx4)
static __device__ __forceinline__ void async16(const void* g, void* l) {
    __builtin_amdgcn_global_load_lds((gptr_t)g, (lptr_t)l, 16, 0, 0);
}

// fp32 -> bf16 bits, round-to-nearest-even (finite inputs only)
static __device__ __forceinline__ short f2bf(float f) {
    unsigned int u = __float_as_uint(f);
    u = (u + 0x7fffu + ((u >> 16) & 1u)) >> 16;
    return (short)u;
}

// ---------------------------------------------------------------------------
// Kernel 0: softmax -> top-k -> renormalize (== softmax over selected logits)
// ---------------------------------------------------------------------------
__global__ void topk_weights_kernel(const float* __restrict__ ql,
                                    const float* __restrict__ kl,
                                    const float* __restrict__ vl,
                                    const int* __restrict__ topk,
                                    int* __restrict__ idx_out,     // [3][16]
                                    float* __restrict__ w_out) {   // [3][16]
    int bank = threadIdx.x;
    if (bank >= 3) return;
    const float* lg = (bank == 0) ? ql : (bank == 1) ? kl : vl;
    int K = *topk; if (K < 1) K = 1; if (K > PMAX) K = PMAX;
    float l[PMAX];
    for (int i = 0; i < PMAX; ++i) l[i] = lg[i];
    bool used[PMAX];
    for (int i = 0; i < PMAX; ++i) used[i] = false;
    int   sel_i[PMAX];
    float sel_l[PMAX];
    for (int j = 0; j < K; ++j) {
        int best = -1; float bv = -INFINITY;
        for (int i = 0; i < PMAX; ++i)
            if (!used[i] && l[i] > bv) { bv = l[i]; best = i; }
        used[best] = true; sel_i[j] = best; sel_l[j] = bv;
    }
    float mx = sel_l[0];
    float e[PMAX];
    float sum = 0.f;
    for (int j = 0; j < K; ++j) { e[j] = __expf(sel_l[j] - mx); sum += e[j]; }
    float inv = 1.f / sum;
    for (int j = 0; j < PMAX; ++j) {
        idx_out[bank * PMAX + j] = (j < K) ? sel_i[j] : 0;
        w_out[bank * PMAX + j]   = (j < K) ? e[j] * inv : 0.f;
    }
}

// ---------------------------------------------------------------------------
// elementwise fp32 -> bf16 (vectorized)
// ---------------------------------------------------------------------------
__global__ __launch_bounds__(256) void convert_bf16_kernel(
    const float* __restrict__ src, short* __restrict__ dst, int n4) {
    int i = blockIdx.x * 256 + threadIdx.x;
    if (i < n4) {
        float4 f = ((const float4*)src)[i];
        short4 o;
        o.x = f2bf(f.x); o.y = f2bf(f.y); o.z = f2bf(f.z); o.w = f2bf(f.w);
        ((short4*)dst)[i] = o;
    }
}

// ---------------------------------------------------------------------------
// prep: build bf16 composition operands (only j < K slots are written/read):
//  z in 0..2: Uc[bank][d][j*64+r]  = U_bank[p_j][d][r]     (direct gather)
//  z in 3..5: Vt[bank][n][j*64+r]  = w_j * V_bank[p_j][r][n]  (LDS transpose)
// ---------------------------------------------------------------------------
__global__ __launch_bounds__(256) void prep_uv_kernel(
    const float* __restrict__ qU, const float* __restrict__ kU,
    const float* __restrict__ vU,
    const float* __restrict__ qV, const float* __restrict__ kV,
    const float* __restrict__ vV,
    const int* __restrict__ idx, const float* __restrict__ wsel,
    const int* __restrict__ topk,
    short* __restrict__ Uc, short* __restrict__ Vt) {
    int z    = blockIdx.z;     // 0..5
    int j    = blockIdx.y;     // 0..15
    int tile = blockIdx.x;     // 0..15
    int t    = threadIdx.x;
    int K = *topk; if (K < 1) K = 1; if (K > PMAX) K = PMAX;
    if (j >= K) return;        // unused primitive slot (uniform per block)
    __shared__ float T[64][65];
    int bank = (z < 3) ? z : z - 3;
    int p = idx[bank * PMAX + j];

    if (z < 3) {
        const float* U = (bank == 0) ? qU : (bank == 1) ? kU : vU;
        const float* src = U + (size_t)p * D_MODEL * RANK;
        short* dst = Uc + (size_t)bank * D_MODEL * KCMAX;
        int r4 = (t & 15) * 4;
        int dl = t >> 4;
#pragma unroll
        for (int i = 0; i < 4; ++i) {
            int d = tile * 64 + i * 16 + dl;
            float4 f = *(const float4*)&src[(size_t)d * RANK + r4];
            short4 o;
            o.x = f2bf(f.x); o.y = f2bf(f.y); o.z = f2bf(f.z); o.w = f2bf(f.w);
            *(short4*)&dst[(size_t)d * KCMAX + j * 64 + r4] = o;
        }
    } else {
        const float* V = (bank == 0) ? qV : (bank == 1) ? kV : vV;
        float wj = wsel[bank * PMAX + j];
        const float* src = V + (size_t)p * RANK * D_MODEL;    // [r][n]
        int n0 = tile * 64;
        int nl = t & 63, rq = t >> 6;
#pragma unroll
        for (int i = 0; i < 16; ++i) {
            int rl = i * 4 + rq;
            T[nl][rl] = src[(size_t)rl * D_MODEL + n0 + nl] * wj;
        }
        __syncthreads();
        short* dst = Vt + (size_t)bank * D_MODEL * KCMAX;
        int rr = t >> 2;
#pragma unroll
        for (int i = 0; i < 4; ++i) {
            int c = (t & 3) * 16 + i * 4;
            short4 o;
            o.x = f2bf(T[rr][c + 0]); o.y = f2bf(T[rr][c + 1]);
            o.z = f2bf(T[rr][c + 2]); o.w = f2bf(T[rr][c + 3]);
            *(short4*)&dst[(size_t)(n0 + rr) * KCMAX + j * 64 + c] = o;
        }
    }
}

// ---------------------------------------------------------------------------
// m97-style bf16 MFMA GEMM tile body: C[128x128] += A[128xkl] * B^T[128xkl]
// ---------------------------------------------------------------------------
static __device__ __forceinline__ void mfma_gemm_tile(
    const short* __restrict__ A, const short* __restrict__ B, int kl,
    int lda, int ldb, int m0, int n0, short* As, short* Bs, floatx4 acc[4][4]) {
    const int t    = threadIdx.x;
    const int w    = t >> 6;
    const int lane = t & 63;
    const int wm   = w & 1, wn = w >> 1;
    const int colL = lane & 15, quad = lane >> 4;
    const int srow  = lane >> 2;        // 0..15
    const int skoff = (lane & 3) * 8;   // 8-short (16B) chunk

#pragma unroll
    for (int i = 0; i < 4; ++i)
#pragma unroll
        for (int j = 0; j < 4; ++j) acc[i][j] = (floatx4){0.f, 0.f, 0.f, 0.f};

    for (int k0 = 0; k0 < kl; k0 += 32) {
        async16(A + (size_t)(m0 + w * 16 + srow) * lda + k0 + skoff,
                As + (w * 16 + srow) * 32 + skoff);
        async16(A + (size_t)(m0 + 64 + w * 16 + srow) * lda + k0 + skoff,
                As + (64 + w * 16 + srow) * 32 + skoff);
        async16(B + (size_t)(n0 + w * 16 + srow) * ldb + k0 + skoff,
                Bs + (w * 16 + srow) * 32 + skoff);
        async16(B + (size_t)(n0 + 64 + w * 16 + srow) * ldb + k0 + skoff,
                Bs + (64 + w * 16 + srow) * 32 + skoff);
        __syncthreads();
        short8v af[4], bf[4];
#pragma unroll
        for (int i = 0; i < 4; ++i)
            af[i] = *(const short8v*)&As[(wm * 64 + i * 16 + colL) * 32 + quad * 8];
#pragma unroll
        for (int j = 0; j < 4; ++j)
            bf[j] = *(const short8v*)&Bs[(wn * 64 + j * 16 + colL) * 32 + quad * 8];
#pragma unroll
        for (int i = 0; i < 4; ++i)
#pragma unroll
            for (int j = 0; j < 4; ++j)
                acc[i][j] = __builtin_amdgcn_mfma_f32_16x16x32_bf16(af[i], bf[j], acc[i][j], 0, 0, 0);
        __syncthreads();
    }
}

// ---------------------------------------------------------------------------
// Kernel 1: Wt[bank][n][d] = W_eff^T = Vt(as A) x Uc(as B), inner K*64.
// ---------------------------------------------------------------------------
__global__ __launch_bounds__(256) void gemm_weff_kernel(
    const short* __restrict__ Vt, const short* __restrict__ Uc,
    const int* __restrict__ topk, short* __restrict__ Wt) {
    int K = *topk; if (K < 1) K = 1; if (K > PMAX) K = PMAX;
    int id = blockIdx.x + 8 * (blockIdx.y + 8 * blockIdx.z);
    int sw = (id & 7) * 24 + (id >> 3);
    int m0 = (sw & 7) * 128; int rest = sw >> 3;
    int n0 = (rest & 7) * 128; int bank = rest >> 3;
    __shared__ short As[128 * 32];
    __shared__ short Bs[128 * 32];
    floatx4 acc[4][4];
    mfma_gemm_tile(Vt + (size_t)bank * D_MODEL * KCMAX,
                   Uc + (size_t)bank * D_MODEL * KCMAX,
                   K * 64, KCMAX, KCMAX, m0, n0, As, Bs, acc);

    const int t = threadIdx.x, w = t >> 6, lane = t & 63;
    const int wm = w & 1, wn = w >> 1, colL = lane & 15, quad = lane >> 4;
    short* Wb = Wt + (size_t)bank * D_MODEL * D_MODEL;
#pragma unroll
    for (int i = 0; i < 4; ++i)
#pragma unroll
        for (int j = 0; j < 4; ++j)
#pragma unroll
            for (int r = 0; r < 4; ++r)
                Wb[(size_t)(m0 + wm * 64 + i * 16 + quad * 4 + r) * D_MODEL +
                   (n0 + wn * 64 + j * 16 + colL)] = f2bf(acc[i][j][r]);
}

// ---------------------------------------------------------------------------
// Kernel 2: qkv[bank] = x @ W_eff[bank] -> bf16 [3][B*H][S][D]
// ---------------------------------------------------------------------------
__global__ __launch_bounds__(256) void gemm_qkv_kernel(
    const short* __restrict__ xb, const short* __restrict__ Wt,
    short* __restrict__ qkv) {
    int id = blockIdx.x + 32 * (blockIdx.y + 8 * blockIdx.z);
    int sw = (id & 7) * 96 + (id >> 3);
    int m0 = (sw & 31) * 128; int rest = sw >> 5;
    int n0 = (rest & 7) * 128; int bank = rest >> 3;
    __shared__ short As[128 * 32];
    __shared__ short Bs[128 * 32];
    floatx4 acc[4][4];
    mfma_gemm_tile(xb, Wt + (size_t)bank * D_MODEL * D_MODEL,
                   D_MODEL, D_MODEL, D_MODEL, m0, n0, As, Bs, acc);

    const int t = threadIdx.x, w = t >> 6, lane = t & 63;
    const int wm = w & 1, wn = w >> 1, colL = lane & 15, quad = lane >> 4;
    short* outp = qkv + (size_t)bank * MROWS * D_MODEL;
#pragma unroll
    for (int i = 0; i < 4; ++i)
#pragma unroll
        for (int j = 0; j < 4; ++j)
#pragma unroll
            for (int r = 0; r < 4; ++r) {
                int m = m0 + wm * 64 + i * 16 + quad * 4 + r;
                int n = n0 + wn * 64 + j * 16 + colL;
                int b = m >> 10, s = m & 1023;
                int head = n >> 6, d = n & 63;
                outp[(((size_t)(b * NHEAD + head) << 10) + s) * HD + d] = f2bf(acc[i][j][r]);
            }
}

// ---------------------------------------------------------------------------
// Kernel 4: out = attn(bf16) @ out_w(bf16)^T -> fp32 d_out
// ---------------------------------------------------------------------------
__global__ __launch_bounds__(256) void gemm_proj_kernel(
    const short* __restrict__ attnb, const short* __restrict__ wb,
    float* __restrict__ outp) {
    int id = blockIdx.x + 32 * blockIdx.y;
    int sw = (id & 7) * 32 + (id >> 3);
    int m0 = (sw & 31) * 128;
    int n0 = (sw >> 5) * 128;
    __shared__ short As[128 * 32];
    __shared__ short Bs[128 * 32];
    floatx4 acc[4][4];
    mfma_gemm_tile(attnb, wb, D_MODEL, D_MODEL, D_MODEL, m0, n0, As, Bs, acc);

    const int t = threadIdx.x, w = t >> 6, lane = t & 63;
    const int wm = w & 1, wn = w >> 1, colL = lane & 15, quad = lane >> 4;
#pragma unroll
    for (int i = 0; i < 4; ++i)
#pragma unroll
        for (int j = 0; j < 4; ++j)
#pragma unroll
            for (int r = 0; r < 4; ++r)
                outp[(size_t)(m0 + wm * 64 + i * 16 + quad * 4 + r) * D_MODEL +
                     (n0 + wn * 64 + j * 16 + colL)] = acc[i][j][r];
}

// ---------------------------------------------------------------------------
// Kernel 3: causal flash attention, swapped-operand QK^T (P stays in regs).
//  - QK: mfma(K_frag, Q_frag) -> lane (col,quad) holds S[q=col][key=16mb+quad*4+r]
//  - softmax: in-lane over 32 regs + shfl_xor(16,32); defer-max THR=8 (exp2 dom)
//  - PV: A = P packed in-lane (key perm квад*4+(e&3)+16(e>>2)); B = V via
//    ds_read_b64_tr_b16 from d-major subtiled LDS (same key perm -> consistent)
//  - K staged async16 with XOR-swizzled source; V staged async16 subtiled.
// ---------------------------------------------------------------------------
__global__ __launch_bounds__(256) void attn_mfma_kernel(
    const short* __restrict__ qkv,    // bf16 [3][BH=64][S=1024][D=64]
    short* __restrict__ attn_out) {   // bf16 [B=4][S=1024][H*D=1024]
    const int t    = threadIdx.x;
    const int w    = t >> 6;
    const int lane = t & 63;
    const int col  = lane & 15;
    const int quad = lane >> 4;
    // XCD swizzle: 512 blocks, chunk 64 -> 8 heads per XCD (KV stays in L2)
    int id = blockIdx.x + 8 * blockIdx.y;
    int swz = (id & 7) * 64 + (id >> 3);
    const int pr = swz & 7;    // 0..7
    const int bh = swz >> 3;   // 0..63
    const size_t HS   = (size_t)S_LEN * HD;
    const size_t BSTR = (size_t)MROWS * D_MODEL;
    const short* Qg = qkv + (size_t)bh * HS;
    const short* Kg = qkv + BSTR + (size_t)bh * HS;
    const short* Vg = qkv + 2 * BSTR + (size_t)bh * HS;

    __shared__ short Ks[128 * 64];   // row-major [key][d], XOR-swizzled slots
    __shared__ short Vs[128 * 64];   // subtiled [d16][k4][4][16]

    const float SC = 0.125f * 1.44269504f;   // 1/sqrt(64) * log2(e)

    // staging decode (loop-invariant): chunk c = t + it*256
    int krow[4], kslot[4], vkey[4], voff[4];
#pragma unroll
    for (int it = 0; it < 4; ++it) {
        int c = t + it * 256;
        krow[it]  = c >> 3;
        kslot[it] = (c & 7) ^ ((c >> 3) & 7);
        int h = c & 1, kr = (c >> 1) & 3, k4 = (c >> 3) & 31, d16 = c >> 8;
        vkey[it] = k4 * 4 + kr;
        voff[it] = d16 * 16 + h * 8;
    }
    const int sw0 = (quad ^ (col & 7)) * 16;          // K read swizzle (bytes)
    const int sw1 = ((4 + quad) ^ (col & 7)) * 16;
    lds3s vb = (lds3s)&Vs[quad * 64 + col * 4];       // tr-read base

    for (int ph = 0; ph < 2; ++ph) {
        const int qt = ph ? (15 - pr) : pr;
        const int qb = qt * 4 + w;
        const int qrow = qt * 64 + w * 16 + col;
        short8v aq0 = *(const short8v*)(Qg + (size_t)qrow * HD + quad * 8);
        short8v aq1 = *(const short8v*)(Qg + (size_t)qrow * HD + 32 + quad * 8);
        floatx4 O0 = {0.f, 0.f, 0.f, 0.f}, O1 = O0, O2 = O0, O3 = O0;
        float mrow = -INFINITY, lrow = 0.f;
        const int nkv = (qt + 2) >> 1;

        for (int jt = 0; jt < nkv; ++jt) {
            __syncthreads();
#pragma unroll
            for (int it = 0; it < 4; ++it) {
                async16(Kg + (size_t)(jt * 128 + krow[it]) * HD + kslot[it] * 8,
                        Ks + (t + it * 256) * 8);
                async16(Vg + (size_t)(jt * 128 + vkey[it]) * HD + voff[it],
                        Vs + (t + it * 256) * 8);
            }
            __syncthreads();

            // ---- swapped QK^T: lane gets S[q=col][key=16mb+quad*4+r] ----
            const int base = jt * 8;
            float s[8][4];
#pragma unroll
            for (int mb = 0; mb < 8; ++mb) {
                int rel = qb - (base + mb);
                if (rel >= 0) {
                    floatx4 c4 = {0.f, 0.f, 0.f, 0.f};
                    const char* kp = (const char*)Ks + mb * 2048 + col * 128;
                    short8v a0 = *(const short8v*)(kp + sw0);
                    short8v a1 = *(const short8v*)(kp + sw1);
                    c4 = __builtin_amdgcn_mfma_f32_16x16x32_bf16(a0, aq0, c4, 0, 0, 0);
                    c4 = __builtin_amdgcn_mfma_f32_16x16x32_bf16(a1, aq1, c4, 0, 0, 0);
#pragma unroll
                    for (int r = 0; r < 4; ++r) {
                        float v = c4[r] * SC;
                        if (rel == 0 && quad * 4 + r > col) v = -INFINITY;
                        s[mb][r] = v;
                    }
                } else {
#pragma unroll
                    for (int r = 0; r < 4; ++r) s[mb][r] = -INFINITY;
                }
            }
            // ---- online softmax, per q-row (q = col), defer-max ----
            float tm = -INFINITY;
#pragma unroll
            for (int mb = 0; mb < 8; ++mb)
#pragma unroll
                for (int r = 0; r < 4; ++r) tm = fmaxf(tm, s[mb][r]);
            tm = fmaxf(tm, __shfl_xor(tm, 16));
            tm = fmaxf(tm, __shfl_xor(tm, 32));
            if (__any(tm > mrow + 8.0f)) {
                float mnew  = fmaxf(mrow, tm);
                float alpha = exp2f(mrow - mnew);
                lrow *= alpha;
                mrow = mnew;
#pragma unroll
                for (int r = 0; r < 4; ++r) {
                    float ar = __shfl(alpha, quad * 4 + r);
                    O0[r] *= ar; O1[r] *= ar; O2[r] *= ar; O3[r] *= ar;
                }
            }
            float p[8][4];
            float ps = 0.f;
#pragma unroll
            for (int mb = 0; mb < 8; ++mb)
#pragma unroll
                for (int r = 0; r < 4; ++r) {
                    float e = exp2f(s[mb][r] - mrow);
                    p[mb][r] = e; ps += e;
                }
            ps += __shfl_xor(ps, 16);
            ps += __shfl_xor(ps, 32);
            lrow += ps;

            // ---- PV: A = packed P (in regs), B = V via tr-reads ----
            int lim = qb * 16 + 15 - (jt << 7);
            int ksm = lim >> 5; if (ksm > 3) ksm = 3;
#pragma unroll
            for (int ks = 0; ks < 4; ++ks) {
                if (ks <= ksm) {
                    lds3s vc = vb + ks * 512;
                    short4v t00, t01, t10, t11, t20, t21, t30, t31;
                    asm volatile("ds_read_b64_tr_b16 %0, %1" : "=v"(t00) : "v"(vc));
                    asm volatile("ds_read_b64_tr_b16 %0, %1" : "=v"(t01) : "v"(vc + 256));
                    asm volatile("ds_read_b64_tr_b16 %0, %1" : "=v"(t10) : "v"(vc + 2048));
                    asm volatile("ds_read_b64_tr_b16 %0, %1" : "=v"(t11) : "v"(vc + 2304));
                    asm volatile("ds_read_b64_tr_b16 %0, %1" : "=v"(t20) : "v"(vc + 4096));
                    asm volatile("ds_read_b64_tr_b16 %0, %1" : "=v"(t21) : "v"(vc + 4352));
                    asm volatile("ds_read_b64_tr_b16 %0, %1" : "=v"(t30) : "v"(vc + 6144));
                    asm volatile("ds_read_b64_tr_b16 %0, %1" : "=v"(t31) : "v"(vc + 6400));
                    short8v ap;
                    ap[0] = f2bf(p[2 * ks][0]);     ap[1] = f2bf(p[2 * ks][1]);
                    ap[2] = f2bf(p[2 * ks][2]);     ap[3] = f2bf(p[2 * ks][3]);
                    ap[4] = f2bf(p[2 * ks + 1][0]); ap[5] = f2bf(p[2 * ks + 1][1]);
                    ap[6] = f2bf(p[2 * ks + 1][2]); ap[7] = f2bf(p[2 * ks + 1][3]);
                    asm volatile("s_waitcnt lgkmcnt(0)" ::: "memory");
                    __builtin_amdgcn_sched_barrier(0);
                    short8v bv0 = __builtin_shufflevector(t00, t01, 0, 1, 2, 3, 4, 5, 6, 7);
                    short8v bv1 = __builtin_shufflevector(t10, t11, 0, 1, 2, 3, 4, 5, 6, 7);
                    short8v bv2 = __builtin_shufflevector(t20, t21, 0, 1, 2, 3, 4, 5, 6, 7);
                    short8v bv3 = __builtin_shufflevector(t30, t31, 0, 1, 2, 3, 4, 5, 6, 7);
                    O0 = __builtin_amdgcn_mfma_f32_16x16x32_bf16(ap, bv0, O0, 0, 0, 0);
                    O1 = __builtin_amdgcn_mfma_f32_16x16x32_bf16(ap, bv1, O1, 0, 0, 0);
                    O2 = __builtin_amdgcn_mfma_f32_16x16x32_bf16(ap, bv2, O2, 0, 0, 0);
                    O3 = __builtin_amdgcn_mfma_f32_16x16x32_bf16(ap, bv3, O3, 0, 0, 0);
                }
            }
        }
        // ---- epilogue: normalize (redistribute 1/l via shfl) + store ----
        const int b  = bh >> 4;
        const int hh = bh & 15;
        short* orow = attn_out +
            ((size_t)(b * S_LEN) + qt * 64 + w * 16) * D_MODEL + hh * 64;
        float linv = 1.f / lrow;
#pragma unroll
        for (int r = 0; r < 4; ++r) {
            float inv = __shfl(linv, quad * 4 + r);
            short* prw = orow + (size_t)(quad * 4 + r) * D_MODEL;
            prw[0  + col] = f2bf(O0[r] * inv);
            prw[16 + col] = f2bf(O1[r] * inv);
            prw[32 + col] = f2bf(O2[r] * inv);
            prw[48 + col] = f2bf(O3[r] * inv);
        }
    }
}

// ---------------------------------------------------------------------------
extern "C" void kernel_launch(void* const* d_in, const int* in_sizes, int n_in,
                              void* d_out, int out_size, void* d_ws, size_t ws_size,
                              hipStream_t stream) {
    const float* x    = (const float*)d_in[0];
    const float* qU   = (const float*)d_in[1];
    const float* qV   = (const float*)d_in[2];
    const float* kU   = (const float*)d_in[3];
    const float* kV   = (const float*)d_in[4];
    const float* vU   = (const float*)d_in[5];
    const float* vV   = (const float*)d_in[6];
    const float* qlg  = (const float*)d_in[7];
    const float* klg  = (const float*)d_in[8];
    const float* vlg  = (const float*)d_in[9];
    const float* outw = (const float*)d_in[10];
    const int*   topk = (const int*)d_in[11];
    float* outp = (float*)d_out;

    char* ws = (char*)d_ws;
    int*   idxp = (int*)ws;                              // [3][16]
    float* wp   = (float*)(ws + 256);                    // [3][16]
    short* xb   = (short*)(ws + 512);                    // 8 MB
    short* Uc   = xb + (size_t)MROWS * D_MODEL;          // 6 MB [3][1024][KCMAX]
    short* Vt   = Uc + (size_t)3 * D_MODEL * KCMAX;      // 6 MB [3][1024][KCMAX]
    short* wb   = Vt + (size_t)3 * D_MODEL * KCMAX;      // 2 MB
    short* Wt   = wb + (size_t)D_MODEL * D_MODEL;        // 6 MB [3][1024][1024]
    short* qkvb = Wt + (size_t)3 * D_MODEL * D_MODEL;    // 24 MB
    short* attnb = qkvb + (size_t)3 * MROWS * D_MODEL;   // 8 MB

    topk_weights_kernel<<<1, 64, 0, stream>>>(qlg, klg, vlg, topk, idxp, wp);
    convert_bf16_kernel<<<(MROWS * D_MODEL / 4 + 255) / 256, 256, 0, stream>>>(
        x, xb, MROWS * D_MODEL / 4);
    convert_bf16_kernel<<<(D_MODEL * D_MODEL / 4 + 255) / 256, 256, 0, stream>>>(
        outw, wb, D_MODEL * D_MODEL / 4);
    prep_uv_kernel<<<dim3(16, 16, 6), 256, 0, stream>>>(
        qU, kU, vU, qV, kV, vV, idxp, wp, topk, Uc, Vt);
    gemm_weff_kernel<<<dim3(8, 8, 3), 256, 0, stream>>>(Vt, Uc, topk, Wt);
    gemm_qkv_kernel<<<dim3(32, 8, 3), 256, 0, stream>>>(xb, Wt, qkvb);
    attn_mfma_kernel<<<dim3(8, 64), 256, 0, stream>>>(qkvb, attnb);
    gemm_proj_kernel<<<dim3(32, 8), 256, 0, stream>>>(attnb, wb, outp);
}